// Round 7
// baseline (340.172 us; speedup 1.0000x reference)
//
#include <hip/hip_runtime.h>

#define B_TREES 128
#define NPT 255
#define NTOT (B_TREES * NPT)   // 32640
#define FIN 64
#define HH 256

typedef short bf16x8 __attribute__((ext_vector_type(8)));
typedef float f32x4  __attribute__((ext_vector_type(4)));
typedef unsigned short u16;

__device__ __forceinline__ float sigf(float x) {
    return __frcp_rn(1.0f + __expf(-x));
}
__device__ __forceinline__ float tanh_fast(float x) {
    return __builtin_fmaf(2.0f, sigf(2.0f * x), -1.0f);
}
__device__ __forceinline__ u16 bf_hi(float v) {       // round-to-nearest-even bf16
    unsigned u = __float_as_uint(v);
    return (u16)((u + 0x7FFFu + ((u >> 16) & 1u)) >> 16);
}
__device__ __forceinline__ float bf_f(u16 b) { return __uint_as_float(((unsigned)b) << 16); }

// ---------------------------------------------------------------------------
// pack_B: B[576 x 1280] in MFMA-B-frag layout, split bf16 hi+lo (as R6), PLUS
// fp32 WxT for the fp32 leaf kernel: WxT[(k>>2)*4096 + j*4 + (k&3)] =
//   j<768 ? Wiou[j][k] : 2*Wf[j-768][k]   (k<64, j<1024)
// ---------------------------------------------------------------------------
__global__ __launch_bounds__(256) void pack_B(
    const float* __restrict__ Uiou, const float* __restrict__ Uf,
    const float* __restrict__ Wiou, const float* __restrict__ Wf,
    u16* __restrict__ Bhi, u16* __restrict__ Blo, float* __restrict__ WxT)
{
    int idx = blockIdx.x * 256 + threadIdx.x;   // grid covers 409600 + 65536
    if (idx < 409600) {
        int j    = idx & 7;
        int lane = (idx >> 3) & 63;
        int ksl  = (idx >> 9) % 10;
        int ct   = idx / 5120;
        int s = ct % 5, hb = ct / 5;
        int n = lane & 15, q = lane >> 4;
        int jH = hb * 16 + n;
        int k = (s < 4 ? ksl * 32 : 320 + ksl * 32) + q * 8 + j;
        float v = 0.0f;
        if (s == 4) {
            if (k < 576) v = Uf[(size_t)jH * HH + (k - 320)];
        } else {
            if (k < 256) {
                v = (s < 3) ? Uiou[(size_t)(s * 256 + jH) * HH + k]
                            : Uf[(size_t)jH * HH + k];
            } else {
                int kw = k - 256;
                v = (s < 3) ? Wiou[(size_t)(s * 256 + jH) * FIN + kw]
                            : 2.0f * Wf[(size_t)jH * FIN + kw];
            }
        }
        u16 hi = bf_hi(v);
        u16 lo = bf_hi(v - bf_f(hi));
        Bhi[idx] = hi;
        Blo[idx] = lo;
    } else {
        int idx2 = idx - 409600;   // < 65536
        int k = idx2 >> 10, j = idx2 & 1023;
        float v = (j < 768) ? Wiou[(size_t)j * 64 + k] : 2.0f * Wf[(size_t)(j - 768) * 64 + k];
        WxT[(size_t)(k >> 2) * 4096 + j * 4 + (k & 3)] = v;
    }
}

// ---------------------------------------------------------------------------
// Leaves, fp32 (R4 design — K=64 only; the MFMA path was 51us latency-bound
// here): iou = W_iou x + b; c = sig(i)*tanh(u); h = sig(o)*tanh(c).
// 16 leaves/block, 1024 blocks x 256 threads.
// ---------------------------------------------------------------------------
__global__ __launch_bounds__(256) void leaf_v2(
    const float* __restrict__ feat,
    const float* __restrict__ WxT, const float* __restrict__ biou,
    float* __restrict__ h, float* __restrict__ c)
{
    const int NB = 16;
    __shared__ float xs[NB][FIN];
    int tid = threadIdx.x;
    int l0 = blockIdx.x * NB;
    int b = l0 >> 7;
    int g0 = b * NPT + 127 + (l0 & 127);
    const float* fb = feat + (size_t)g0 * FIN;
    for (int i = tid; i < NB * FIN; i += 256) ((float*)xs)[i] = fb[i];
    __syncthreads();

    float ai[NB], ao[NB], au[NB];
#pragma unroll
    for (int n = 0; n < NB; ++n) { ai[n] = 0.f; ao[n] = 0.f; au[n] = 0.f; }

    const float4* WxT4 = (const float4*)WxT;
    for (int k4 = 0; k4 < 16; ++k4) {
        size_t base = (size_t)k4 * 1024 + tid;
        float4 wi = WxT4[base], wo = WxT4[base + 256], wu = WxT4[base + 512];
#pragma unroll
        for (int n = 0; n < NB; ++n) {
            float4 x4 = ((const float4*)xs[n])[k4];
            ai[n] += wi.x * x4.x + wi.y * x4.y + wi.z * x4.z + wi.w * x4.w;
            ao[n] += wo.x * x4.x + wo.y * x4.y + wo.z * x4.z + wo.w * x4.w;
            au[n] += wu.x * x4.x + wu.y * x4.y + wu.z * x4.z + wu.w * x4.w;
        }
    }

    float bi = biou[tid], bo = biou[tid + 256], bu = biou[tid + 512];
#pragma unroll
    for (int n = 0; n < NB; ++n) {
        float iv = sigf(ai[n] + bi);
        float ov = sigf(ao[n] + bo);
        float uv = tanh_fast(au[n] + bu);
        float cv = iv * uv;
        float hv = ov * tanh_fast(cv);
        c[(size_t)(g0 + n) * HH + tid] = cv;
        h[(size_t)(g0 + n) * HH + tid] = hv;
    }
}

// ---------------------------------------------------------------------------
// level_mfma (R6, verified): 256 thr = 4 waves, 32 nodes/block, split-bf16.
// Used for t=1 (NCT=10, CSPLIT=2) and t=2 (NCT=5, CSPLIT=4).
// ---------------------------------------------------------------------------
template<int NCT>
__global__ __launch_bounds__(256, 2) void level_mfma(
    const float* __restrict__ feat,
    const u16* __restrict__ Bhi, const u16* __restrict__ Blo,
    const float* __restrict__ biou, const float* __restrict__ bfv,
    float* __restrict__ h, float* __restrict__ c,
    int Lt, int lg)
{
    constexpr int CSPLIT = 20 / NCT;
    constexpr int SUBS = NCT / 5;
    __shared__ char smem[73728];
    short* Ahi = (short*)smem;
    short* Alo = (short*)(smem + 36864);

    const int tid = threadIdx.x;
    const int lane = tid & 63, w = tid >> 6;
    const int cs = blockIdx.x % CSPLIT;
    const int rb = blockIdx.x / CSPLIT;
    const int m0 = rb * 32;
    const int msk = (1 << lg) - 1;
    const int ctbase = cs * 4 * NCT + w * NCT;

    const float4* Hf4 = (const float4*)h;
    const float4* Ff4 = (const float4*)feat;

    for (int rep = 0; rep < 8; ++rep) {            // hs/hd: 32 m x 64 float4
        int flat = rep * 256 + tid;
        int m = flat >> 6, f4 = flat & 63;
        int mg = m0 + m;
        int b = mg >> lg, ii = Lt + (mg & msk);
        int gc = b * NPT + 2 * ii + 1;
        float4 h1 = Hf4[(size_t)gc * 64 + f4];
        float4 h2 = Hf4[(size_t)(gc + 1) * 64 + f4];
        float hsv[4] = {h1.x + h2.x, h1.y + h2.y, h1.z + h2.z, h1.w + h2.w};
        float hdv[4] = {h1.x - h2.x, h1.y - h2.y, h1.z - h2.z, h1.w - h2.w};
        int rt = m >> 4, lm = m & 15;
        int ks = f4 >> 3;
        int lane_ = lm + 16 * ((f4 >> 1) & 3);
        int j0 = (f4 & 1) * 4;
        ushort4 sh, sl, dh, dl;
        u16* shp = (u16*)&sh; u16* slp = (u16*)&sl;
        u16* dhp = (u16*)&dh; u16* dlp = (u16*)&dl;
#pragma unroll
        for (int e = 0; e < 4; ++e) {
            u16 a = bf_hi(hsv[e]); shp[e] = a; slp[e] = bf_hi(hsv[e] - bf_f(a));
            u16 d = bf_hi(hdv[e]); dhp[e] = d; dlp[e] = bf_hi(hdv[e] - bf_f(d));
        }
        int base_s = ((rt * 18 + ks) * 64 + lane_) * 8 + j0;
        int base_d = ((rt * 18 + ks + 10) * 64 + lane_) * 8 + j0;
        *(ushort4*)&Ahi[base_s] = sh;  *(ushort4*)&Alo[base_s] = sl;
        *(ushort4*)&Ahi[base_d] = dh;  *(ushort4*)&Alo[base_d] = dl;
    }
    for (int rep = 0; rep < 2; ++rep) {            // x: 32 m x 16 float4
        int flat = rep * 256 + tid;
        int m = flat >> 4, f4 = flat & 15;
        int mg = m0 + m;
        int b = mg >> lg, ii = Lt + (mg & msk);
        int g = b * NPT + ii;
        float4 x4 = Ff4[(size_t)g * 16 + f4];
        float xv[4] = {x4.x, x4.y, x4.z, x4.w};
        int rt = m >> 4, lm = m & 15;
        int ks = 8 + (f4 >> 3);
        int lane_ = lm + 16 * ((f4 >> 1) & 3);
        int j0 = (f4 & 1) * 4;
        ushort4 xh, xl;
        u16* xhp = (u16*)&xh; u16* xlp = (u16*)&xl;
#pragma unroll
        for (int e = 0; e < 4; ++e) {
            u16 a = bf_hi(xv[e]); xhp[e] = a; xlp[e] = bf_hi(xv[e] - bf_f(a));
        }
        int base = ((rt * 18 + ks) * 64 + lane_) * 8 + j0;
        *(ushort4*)&Ahi[base] = xh;  *(ushort4*)&Alo[base] = xl;
    }
    __syncthreads();

    f32x4 acc[2][NCT];
#pragma unroll
    for (int rt = 0; rt < 2; ++rt)
#pragma unroll
        for (int i = 0; i < NCT; ++i) acc[rt][i] = (f32x4){0.f, 0.f, 0.f, 0.f};

    for (int G = 0; G < 10; ++G) {
        bf16x8 ah[2], al[2];
#pragma unroll
        for (int rt = 0; rt < 2; ++rt) {
            ah[rt] = *(const bf16x8*)&Ahi[((rt * 18 + G) * 64 + lane) * 8];
            al[rt] = *(const bf16x8*)&Alo[((rt * 18 + G) * 64 + lane) * 8];
        }
#pragma unroll
        for (int ctl = 0; ctl < NCT; ++ctl) {
            if (ctl % 5 == 4) continue;
            size_t slot = (size_t)((ctbase + ctl) * 10 + G) * 512 + lane * 8;
            bf16x8 bh = *(const bf16x8*)(Bhi + slot);
            bf16x8 bl = *(const bf16x8*)(Blo + slot);
#pragma unroll
            for (int rt = 0; rt < 2; ++rt) {
                acc[rt][ctl] = __builtin_amdgcn_mfma_f32_16x16x32_bf16(ah[rt], bh, acc[rt][ctl], 0, 0, 0);
                acc[rt][ctl] = __builtin_amdgcn_mfma_f32_16x16x32_bf16(ah[rt], bl, acc[rt][ctl], 0, 0, 0);
                acc[rt][ctl] = __builtin_amdgcn_mfma_f32_16x16x32_bf16(al[rt], bh, acc[rt][ctl], 0, 0, 0);
            }
        }
    }
    for (int G = 10; G < 18; ++G) {
        bf16x8 ah[2], al[2];
#pragma unroll
        for (int rt = 0; rt < 2; ++rt) {
            ah[rt] = *(const bf16x8*)&Ahi[((rt * 18 + G) * 64 + lane) * 8];
            al[rt] = *(const bf16x8*)&Alo[((rt * 18 + G) * 64 + lane) * 8];
        }
#pragma unroll
        for (int ctl = 4; ctl < NCT; ctl += 5) {
            size_t slot = (size_t)((ctbase + ctl) * 10 + (G - 10)) * 512 + lane * 8;
            bf16x8 bh = *(const bf16x8*)(Bhi + slot);
            bf16x8 bl = *(const bf16x8*)(Blo + slot);
#pragma unroll
            for (int rt = 0; rt < 2; ++rt) {
                acc[rt][ctl] = __builtin_amdgcn_mfma_f32_16x16x32_bf16(ah[rt], bh, acc[rt][ctl], 0, 0, 0);
                acc[rt][ctl] = __builtin_amdgcn_mfma_f32_16x16x32_bf16(ah[rt], bl, acc[rt][ctl], 0, 0, 0);
                acc[rt][ctl] = __builtin_amdgcn_mfma_f32_16x16x32_bf16(al[rt], bh, acc[rt][ctl], 0, 0, 0);
            }
        }
    }
    __syncthreads();

    float* sc = (float*)smem + w * 2592;       // [32 rows][81] per wave (aliased over A)
    const int n = lane & 15, q = lane >> 4;
#pragma unroll
    for (int sub = 0; sub < SUBS; ++sub) {
#pragma unroll
        for (int rt = 0; rt < 2; ++rt)
#pragma unroll
            for (int s = 0; s < 5; ++s) {
                f32x4 v = acc[rt][sub * 5 + s];
#pragma unroll
                for (int r = 0; r < 4; ++r)
                    sc[(rt * 16 + q * 4 + r) * 81 + s * 16 + n] = v[r];
            }
        int hb_abs = ctbase / 5 + sub;
        int jHb = hb_abs * 16;
        for (int it = 0; it < 8; ++it) {
            int idx = it * 64 + lane;
            int m = idx >> 4, jl = idx & 15;
            int jH = jHb + jl;
            float Ci  = sc[m * 81 + jl];
            float Co  = sc[m * 81 + 16 + jl];
            float Cu  = sc[m * 81 + 32 + jl];
            float Cfs = sc[m * 81 + 48 + jl];
            float Cfd = sc[m * 81 + 64 + jl];
            int mg = m0 + m;
            int b = mg >> lg, ii = Lt + (mg & msk);
            size_t g = (size_t)b * NPT + ii;
            float iv = sigf(Ci + biou[jH]);
            float ov = sigf(Co + biou[256 + jH]);
            float uv = tanh_fast(Cu + biou[512 + jH]);
            size_t gc = g + ii + 1;
            float bF = bfv[jH];
            float f1 = sigf(0.5f * (Cfs + Cfd) + bF);
            float f2 = sigf(0.5f * (Cfs - Cfd) + bF);
            float cv = iv * uv + f1 * c[gc * HH + jH] + f2 * c[(gc + 1) * HH + jH];
            float hv = ov * tanh_fast(cv);
            c[g * HH + jH] = cv;
            h[g * HH + jH] = hv;
        }
    }
}

// ---------------------------------------------------------------------------
// mfma_tail: t=3..7 (nt = 16,8,4,2,1 per tree) in ONE dispatch.
// 64 blocks x 512 thr (8 waves), 2 trees/block: A rows 0..15 = tree0, 16..31
// = tree1. Wave w handles hb in {w, w+8} sequentially (acc[2][5] = 40 VGPR).
// Child h/c via global with __syncthreads() workgroup visibility.
// Scratch lives AFTER the A region (no aliasing barriers).
// ---------------------------------------------------------------------------
template<int NT>
__device__ __forceinline__ void tail_level(
    int gb0, int gb1,
    const float* __restrict__ feat,
    const u16* __restrict__ Bhi, const u16* __restrict__ Blo,
    const float* __restrict__ biou, const float* __restrict__ bfv,
    float* __restrict__ h, float* __restrict__ c, char* smem)
{
    short* Ahi = (short*)smem;
    short* Alo = (short*)(smem + 36864);
    const int tid = threadIdx.x;
    const int lane = tid & 63, w = tid >> 6;
    const int first = NT - 1;
    constexpr int LOG = (NT == 16) ? 4 : (NT == 8) ? 3 : (NT == 4) ? 2 : (NT == 2) ? 1 : 0;

    const float4* Hf4 = (const float4*)h;
    const float4* Ff4 = (const float4*)feat;

    // stage hs/hd
    for (int i = tid; i < 2 * NT * 64; i += 512) {
        int f4 = i & 63, r = i >> 6;
        int t = r >> LOG, lm = r & (NT - 1);
        int gb = t ? gb1 : gb0;
        int ii = first + lm;
        int gc = gb + 2 * ii + 1;
        float4 h1 = Hf4[(size_t)gc * 64 + f4];
        float4 h2 = Hf4[(size_t)(gc + 1) * 64 + f4];
        float hsv[4] = {h1.x + h2.x, h1.y + h2.y, h1.z + h2.z, h1.w + h2.w};
        float hdv[4] = {h1.x - h2.x, h1.y - h2.y, h1.z - h2.z, h1.w - h2.w};
        int ks = f4 >> 3;
        int lane_ = lm + 16 * ((f4 >> 1) & 3);
        int j0 = (f4 & 1) * 4;
        ushort4 sh, sl, dh, dl;
        u16* shp = (u16*)&sh; u16* slp = (u16*)&sl;
        u16* dhp = (u16*)&dh; u16* dlp = (u16*)&dl;
#pragma unroll
        for (int e = 0; e < 4; ++e) {
            u16 a = bf_hi(hsv[e]); shp[e] = a; slp[e] = bf_hi(hsv[e] - bf_f(a));
            u16 d = bf_hi(hdv[e]); dhp[e] = d; dlp[e] = bf_hi(hdv[e] - bf_f(d));
        }
        int base_s = ((t * 18 + ks) * 64 + lane_) * 8 + j0;
        int base_d = ((t * 18 + ks + 10) * 64 + lane_) * 8 + j0;
        *(ushort4*)&Ahi[base_s] = sh;  *(ushort4*)&Alo[base_s] = sl;
        *(ushort4*)&Ahi[base_d] = dh;  *(ushort4*)&Alo[base_d] = dl;
    }
    // stage x
    for (int i = tid; i < 2 * NT * 16; i += 512) {
        int f4 = i & 15, r = i >> 4;
        int t = r >> LOG, lm = r & (NT - 1);
        int gb = t ? gb1 : gb0;
        int g = gb + first + lm;
        float4 x4 = Ff4[(size_t)g * 16 + f4];
        float xv[4] = {x4.x, x4.y, x4.z, x4.w};
        int ks = 8 + (f4 >> 3);
        int lane_ = lm + 16 * ((f4 >> 1) & 3);
        int j0 = (f4 & 1) * 4;
        ushort4 xh, xl;
        u16* xhp = (u16*)&xh; u16* xlp = (u16*)&xl;
#pragma unroll
        for (int e = 0; e < 4; ++e) {
            u16 a = bf_hi(xv[e]); xhp[e] = a; xlp[e] = bf_hi(xv[e] - bf_f(a));
        }
        int base = ((t * 18 + ks) * 64 + lane_) * 8 + j0;
        *(ushort4*)&Ahi[base] = xh;  *(ushort4*)&Alo[base] = xl;
    }
    __syncthreads();

    float* sc = (float*)(smem + 73728) + w * 1296;  // 16 rows x 81 per wave
    const int n = lane & 15, q = lane >> 4;

    for (int hbi = 0; hbi < 2; ++hbi) {
        int hb = (w & 7) + 8 * hbi;
        f32x4 acc[2][5];
#pragma unroll
        for (int rt = 0; rt < 2; ++rt)
#pragma unroll
            for (int s = 0; s < 5; ++s) acc[rt][s] = (f32x4){0.f, 0.f, 0.f, 0.f};

        for (int G = 0; G < 10; ++G) {
            bf16x8 ah[2], al[2];
#pragma unroll
            for (int rt = 0; rt < 2; ++rt) {
                ah[rt] = *(const bf16x8*)&Ahi[((rt * 18 + G) * 64 + lane) * 8];
                al[rt] = *(const bf16x8*)&Alo[((rt * 18 + G) * 64 + lane) * 8];
            }
#pragma unroll
            for (int s = 0; s < 4; ++s) {
                size_t slot = (size_t)((hb * 5 + s) * 10 + G) * 512 + lane * 8;
                bf16x8 bh = *(const bf16x8*)(Bhi + slot);
                bf16x8 bl = *(const bf16x8*)(Blo + slot);
#pragma unroll
                for (int rt = 0; rt < 2; ++rt) {
                    acc[rt][s] = __builtin_amdgcn_mfma_f32_16x16x32_bf16(ah[rt], bh, acc[rt][s], 0, 0, 0);
                    acc[rt][s] = __builtin_amdgcn_mfma_f32_16x16x32_bf16(ah[rt], bl, acc[rt][s], 0, 0, 0);
                    acc[rt][s] = __builtin_amdgcn_mfma_f32_16x16x32_bf16(al[rt], bh, acc[rt][s], 0, 0, 0);
                }
            }
        }
        for (int G = 10; G < 18; ++G) {
            bf16x8 ah[2], al[2];
#pragma unroll
            for (int rt = 0; rt < 2; ++rt) {
                ah[rt] = *(const bf16x8*)&Ahi[((rt * 18 + G) * 64 + lane) * 8];
                al[rt] = *(const bf16x8*)&Alo[((rt * 18 + G) * 64 + lane) * 8];
            }
            size_t slot = (size_t)((hb * 5 + 4) * 10 + (G - 10)) * 512 + lane * 8;
            bf16x8 bh = *(const bf16x8*)(Bhi + slot);
            bf16x8 bl = *(const bf16x8*)(Blo + slot);
#pragma unroll
            for (int rt = 0; rt < 2; ++rt) {
                acc[rt][4] = __builtin_amdgcn_mfma_f32_16x16x32_bf16(ah[rt], bh, acc[rt][4], 0, 0, 0);
                acc[rt][4] = __builtin_amdgcn_mfma_f32_16x16x32_bf16(ah[rt], bl, acc[rt][4], 0, 0, 0);
                acc[rt][4] = __builtin_amdgcn_mfma_f32_16x16x32_bf16(al[rt], bh, acc[rt][4], 0, 0, 0);
            }
        }

        // epilogue for this hb (wave-private scratch; rt sequential)
        for (int rt = 0; rt < 2; ++rt) {
#pragma unroll
            for (int s = 0; s < 5; ++s) {
                f32x4 v = acc[rt][s];
#pragma unroll
                for (int r = 0; r < 4; ++r)
                    sc[(q * 4 + r) * 81 + s * 16 + n] = v[r];
            }
            int gb = rt ? gb1 : gb0;
            for (int it = 0; it < 4; ++it) {
                int idx = it * 64 + lane;
                int lm = idx >> 4, jl = idx & 15;
                if (lm < NT) {
                    int jH = hb * 16 + jl;
                    float Ci  = sc[lm * 81 + jl];
                    float Co  = sc[lm * 81 + 16 + jl];
                    float Cu  = sc[lm * 81 + 32 + jl];
                    float Cfs = sc[lm * 81 + 48 + jl];
                    float Cfd = sc[lm * 81 + 64 + jl];
                    int ii = first + lm;
                    size_t g = (size_t)gb + ii;
                    size_t gc = (size_t)gb + 2 * ii + 1;
                    float iv = sigf(Ci + biou[jH]);
                    float ov = sigf(Co + biou[256 + jH]);
                    float uv = tanh_fast(Cu + biou[512 + jH]);
                    float bF = bfv[jH];
                    float f1 = sigf(0.5f * (Cfs + Cfd) + bF);
                    float f2 = sigf(0.5f * (Cfs - Cfd) + bF);
                    float cv = iv * uv + f1 * c[gc * HH + jH] + f2 * c[(gc + 1) * HH + jH];
                    float hv = ov * tanh_fast(cv);
                    c[g * HH + jH] = cv;
                    h[g * HH + jH] = hv;
                }
            }
        }
    }
    __syncthreads();   // global h/c visible to whole block; A/scratch reusable
}

__global__ __launch_bounds__(512, 2) void mfma_tail(
    const float* __restrict__ feat,
    const u16* __restrict__ Bhi, const u16* __restrict__ Blo,
    const float* __restrict__ biou, const float* __restrict__ bfv,
    float* __restrict__ h, float* __restrict__ c)
{
    __shared__ char smem[73728 + 41472];   // A hi/lo + 8-wave scratch
    int gb0 = 2 * blockIdx.x * NPT, gb1 = gb0 + NPT;
    tail_level<16>(gb0, gb1, feat, Bhi, Blo, biou, bfv, h, c, smem);
    tail_level<8>(gb0, gb1, feat, Bhi, Blo, biou, bfv, h, c, smem);
    tail_level<4>(gb0, gb1, feat, Bhi, Blo, biou, bfv, h, c, smem);
    tail_level<2>(gb0, gb1, feat, Bhi, Blo, biou, bfv, h, c, smem);
    tail_level<1>(gb0, gb1, feat, Bhi, Blo, biou, bfv, h, c, smem);
}

// ---------------------------------------------------------------------------
// Head, 2-phase. Phase 1: 1024 blocks (8/tree) partial row-sums (full chip).
// Phase 2: 128 blocks combine + lin0 + ReLU + lin1.
// ---------------------------------------------------------------------------
__global__ __launch_bounds__(256) void head_partial(
    const float* __restrict__ h, float* __restrict__ hp)
{
    int blk = blockIdx.x;
    int b = blk >> 3, p = blk & 7, tid = threadIdx.x;
    const float* hb = h + ((size_t)b * NPT + p * 32) * HH;
    int rows = (p == 7) ? 31 : 32;
    float a0 = 0.f, a1 = 0.f, a2 = 0.f, a3 = 0.f;
    int i = 0;
    for (; i + 3 < rows; i += 4) {
        a0 += hb[(size_t)(i + 0) * HH + tid];
        a1 += hb[(size_t)(i + 1) * HH + tid];
        a2 += hb[(size_t)(i + 2) * HH + tid];
        a3 += hb[(size_t)(i + 3) * HH + tid];
    }
    for (; i < rows; ++i) a0 += hb[(size_t)i * HH + tid];
    hp[(size_t)blk * HH + tid] = a0 + a1 + a2 + a3;
}

__global__ __launch_bounds__(256) void head_final(
    const float* __restrict__ hp,
    const float* __restrict__ l0w, const float* __restrict__ l0b,
    const float* __restrict__ l1w, const float* __restrict__ l1b,
    float* __restrict__ out)
{
    __shared__ float ms[HH];
    __shared__ float red[4];
    int b = blockIdx.x, tid = threadIdx.x;
    float a = 0.f;
#pragma unroll
    for (int p = 0; p < 8; ++p) a += hp[(size_t)(b * 8 + p) * HH + tid];
    ms[tid] = a * (1.0f / (float)NPT);
    __syncthreads();

    const float4* L0 = (const float4*)(l0w + (size_t)tid * HH);
    float y = 0.f;
    for (int k4 = 0; k4 < 64; ++k4) {
        float4 wv = L0[k4];
        float4 m4 = ((const float4*)ms)[k4];
        y += wv.x * m4.x + wv.y * m4.y + wv.z * m4.z + wv.w * m4.w;
    }
    y += l0b[tid];
    y = fmaxf(y, 0.f);
    float v = y * l1w[tid];
    for (int off = 32; off > 0; off >>= 1) v += __shfl_down(v, off, 64);
    if ((tid & 63) == 0) red[tid >> 6] = v;
    __syncthreads();
    if (tid == 0) out[b] = red[0] + red[1] + red[2] + red[3] + l1b[0];
}

// ---------------------------------------------------------------------------
extern "C" void kernel_launch(void* const* d_in, const int* in_sizes, int n_in,
                              void* d_out, int out_size, void* d_ws, size_t ws_size,
                              hipStream_t stream)
{
    const float* feat = (const float*)d_in[0];
    const float* Wiou = (const float*)d_in[4];
    const float* biou = (const float*)d_in[5];
    const float* Uiou = (const float*)d_in[6];
    const float* Wf   = (const float*)d_in[7];
    const float* bfv  = (const float*)d_in[8];
    const float* Uf   = (const float*)d_in[9];
    const float* l0w  = (const float*)d_in[10];
    const float* l0b  = (const float*)d_in[11];
    const float* l1w  = (const float*)d_in[12];
    const float* l1b  = (const float*)d_in[13];

    float* h  = (float*)d_ws;
    float* c  = h + (size_t)NTOT * HH;
    u16* Bhi  = (u16*)(c + (size_t)NTOT * HH);
    u16* Blo  = Bhi + 409600;
    float* WxT = (float*)(Blo + 409600);
    float* hp  = WxT + 65536;

    // pack B (split bf16) + WxT (fp32, leaf): 409600 + 65536 elems
    pack_B<<<1856, 256, 0, stream>>>(Uiou, Uf, Wiou, Wf, Bhi, Blo, WxT);

    // leaves: fp32, 16/block
    leaf_v2<<<1024, 256, 0, stream>>>(feat, WxT, biou, h, c);
    // t=1: M=8192, NCT=10 (CSPLIT=2) -> 512 blocks
    level_mfma<10><<<512, 256, 0, stream>>>(feat, Bhi, Blo, biou, bfv, h, c, 63, 6);
    // t=2: M=4096, NCT=5 (CSPLIT=4) -> 512 blocks
    level_mfma<5><<<512, 256, 0, stream>>>(feat, Bhi, Blo, biou, bfv, h, c, 31, 5);
    // t=3..7 merged: 64 blocks x 512 thr, 2 trees/block
    mfma_tail<<<64, 512, 0, stream>>>(feat, Bhi, Blo, biou, bfv, h, c);

    head_partial<<<1024, 256, 0, stream>>>(h, hp);
    head_final<<<B_TREES, 256, 0, stream>>>(hp, l0w, l0b, l1w, l1b, (float*)d_out);
}

// Round 8
// 297.585 us; speedup vs baseline: 1.1431x; 1.1431x over previous
//
#include <hip/hip_runtime.h>

#define B_TREES 128
#define NPT 255
#define NTOT (B_TREES * NPT)   // 32640
#define FIN 64
#define HH 256

typedef short bf16x8 __attribute__((ext_vector_type(8)));
typedef float f32x4  __attribute__((ext_vector_type(4)));
typedef unsigned short u16;

__device__ __forceinline__ float sigf(float x) {
    return __frcp_rn(1.0f + __expf(-x));
}
__device__ __forceinline__ float tanh_fast(float x) {
    return __builtin_fmaf(2.0f, sigf(2.0f * x), -1.0f);
}
__device__ __forceinline__ u16 bf_hi(float v) {       // round-to-nearest-even bf16
    unsigned u = __float_as_uint(v);
    return (u16)((u + 0x7FFFu + ((u >> 16) & 1u)) >> 16);
}
__device__ __forceinline__ float bf_f(u16 b) { return __uint_as_float(((unsigned)b) << 16); }

// ---------------------------------------------------------------------------
// pack_B: B[576 x 1280] in MFMA-B-frag layout, split bf16 hi+lo, PLUS fp32
// WxT for the fp32 leaf kernel.
// ---------------------------------------------------------------------------
__global__ __launch_bounds__(256) void pack_B(
    const float* __restrict__ Uiou, const float* __restrict__ Uf,
    const float* __restrict__ Wiou, const float* __restrict__ Wf,
    u16* __restrict__ Bhi, u16* __restrict__ Blo, float* __restrict__ WxT)
{
    int idx = blockIdx.x * 256 + threadIdx.x;   // grid covers 409600 + 65536
    if (idx < 409600) {
        int j    = idx & 7;
        int lane = (idx >> 3) & 63;
        int ksl  = (idx >> 9) % 10;
        int ct   = idx / 5120;
        int s = ct % 5, hb = ct / 5;
        int n = lane & 15, q = lane >> 4;
        int jH = hb * 16 + n;
        int k = (s < 4 ? ksl * 32 : 320 + ksl * 32) + q * 8 + j;
        float v = 0.0f;
        if (s == 4) {
            if (k < 576) v = Uf[(size_t)jH * HH + (k - 320)];
        } else {
            if (k < 256) {
                v = (s < 3) ? Uiou[(size_t)(s * 256 + jH) * HH + k]
                            : Uf[(size_t)jH * HH + k];
            } else {
                int kw = k - 256;
                v = (s < 3) ? Wiou[(size_t)(s * 256 + jH) * FIN + kw]
                            : 2.0f * Wf[(size_t)jH * FIN + kw];
            }
        }
        u16 hi = bf_hi(v);
        u16 lo = bf_hi(v - bf_f(hi));
        Bhi[idx] = hi;
        Blo[idx] = lo;
    } else {
        int idx2 = idx - 409600;   // < 65536
        int k = idx2 >> 10, j = idx2 & 1023;
        float v = (j < 768) ? Wiou[(size_t)j * 64 + k] : 2.0f * Wf[(size_t)(j - 768) * 64 + k];
        WxT[(size_t)(k >> 2) * 4096 + j * 4 + (k & 3)] = v;
    }
}

// ---------------------------------------------------------------------------
// Leaves, fp32 (K=64 only; MFMA path was 51us latency-bound here).
// 16 leaves/block, 1024 blocks x 256 threads.
// ---------------------------------------------------------------------------
__global__ __launch_bounds__(256) void leaf_v2(
    const float* __restrict__ feat,
    const float* __restrict__ WxT, const float* __restrict__ biou,
    float* __restrict__ h, float* __restrict__ c)
{
    const int NB = 16;
    __shared__ float xs[NB][FIN];
    int tid = threadIdx.x;
    int l0 = blockIdx.x * NB;
    int b = l0 >> 7;
    int g0 = b * NPT + 127 + (l0 & 127);
    const float* fb = feat + (size_t)g0 * FIN;
    for (int i = tid; i < NB * FIN; i += 256) ((float*)xs)[i] = fb[i];
    __syncthreads();

    float ai[NB], ao[NB], au[NB];
#pragma unroll
    for (int n = 0; n < NB; ++n) { ai[n] = 0.f; ao[n] = 0.f; au[n] = 0.f; }

    const float4* WxT4 = (const float4*)WxT;
    for (int k4 = 0; k4 < 16; ++k4) {
        size_t base = (size_t)k4 * 1024 + tid;
        float4 wi = WxT4[base], wo = WxT4[base + 256], wu = WxT4[base + 512];
#pragma unroll
        for (int n = 0; n < NB; ++n) {
            float4 x4 = ((const float4*)xs[n])[k4];
            ai[n] += wi.x * x4.x + wi.y * x4.y + wi.z * x4.z + wi.w * x4.w;
            ao[n] += wo.x * x4.x + wo.y * x4.y + wo.z * x4.z + wo.w * x4.w;
            au[n] += wu.x * x4.x + wu.y * x4.y + wu.z * x4.z + wu.w * x4.w;
        }
    }

    float bi = biou[tid], bo = biou[tid + 256], bu = biou[tid + 512];
#pragma unroll
    for (int n = 0; n < NB; ++n) {
        float iv = sigf(ai[n] + bi);
        float ov = sigf(ao[n] + bo);
        float uv = tanh_fast(au[n] + bu);
        float cv = iv * uv;
        float hv = ov * tanh_fast(cv);
        c[(size_t)(g0 + n) * HH + tid] = cv;
        h[(size_t)(g0 + n) * HH + tid] = hv;
    }
}

// ---------------------------------------------------------------------------
// level_mfma (R6, verified): 256 thr = 4 waves, 32 nodes/block, split-bf16.
// t=1: NCT=10 (CSPLIT=2); t=2..7: NCT=5 (CSPLIT=4).
// NOTE (R7 lesson): do NOT collapse the column split for the deep levels —
// per-block B-stream (1.6 MB) through one CU's L2 port is a ~26 us/level
// wall (mfma_tail measured 134 us for 5 levels at 64 blocks).
// ---------------------------------------------------------------------------
template<int NCT>
__global__ __launch_bounds__(256, 2) void level_mfma(
    const float* __restrict__ feat,
    const u16* __restrict__ Bhi, const u16* __restrict__ Blo,
    const float* __restrict__ biou, const float* __restrict__ bfv,
    float* __restrict__ h, float* __restrict__ c,
    int Lt, int lg)
{
    constexpr int CSPLIT = 20 / NCT;
    constexpr int SUBS = NCT / 5;
    __shared__ char smem[73728];
    short* Ahi = (short*)smem;
    short* Alo = (short*)(smem + 36864);

    const int tid = threadIdx.x;
    const int lane = tid & 63, w = tid >> 6;
    const int cs = blockIdx.x % CSPLIT;
    const int rb = blockIdx.x / CSPLIT;
    const int m0 = rb * 32;
    const int msk = (1 << lg) - 1;
    const int ctbase = cs * 4 * NCT + w * NCT;

    const float4* Hf4 = (const float4*)h;
    const float4* Ff4 = (const float4*)feat;

    for (int rep = 0; rep < 8; ++rep) {            // hs/hd: 32 m x 64 float4
        int flat = rep * 256 + tid;
        int m = flat >> 6, f4 = flat & 63;
        int mg = m0 + m;
        int b = mg >> lg, ii = Lt + (mg & msk);
        int gc = b * NPT + 2 * ii + 1;
        float4 h1 = Hf4[(size_t)gc * 64 + f4];
        float4 h2 = Hf4[(size_t)(gc + 1) * 64 + f4];
        float hsv[4] = {h1.x + h2.x, h1.y + h2.y, h1.z + h2.z, h1.w + h2.w};
        float hdv[4] = {h1.x - h2.x, h1.y - h2.y, h1.z - h2.z, h1.w - h2.w};
        int rt = m >> 4, lm = m & 15;
        int ks = f4 >> 3;
        int lane_ = lm + 16 * ((f4 >> 1) & 3);
        int j0 = (f4 & 1) * 4;
        ushort4 sh, sl, dh, dl;
        u16* shp = (u16*)&sh; u16* slp = (u16*)&sl;
        u16* dhp = (u16*)&dh; u16* dlp = (u16*)&dl;
#pragma unroll
        for (int e = 0; e < 4; ++e) {
            u16 a = bf_hi(hsv[e]); shp[e] = a; slp[e] = bf_hi(hsv[e] - bf_f(a));
            u16 d = bf_hi(hdv[e]); dhp[e] = d; dlp[e] = bf_hi(hdv[e] - bf_f(d));
        }
        int base_s = ((rt * 18 + ks) * 64 + lane_) * 8 + j0;
        int base_d = ((rt * 18 + ks + 10) * 64 + lane_) * 8 + j0;
        *(ushort4*)&Ahi[base_s] = sh;  *(ushort4*)&Alo[base_s] = sl;
        *(ushort4*)&Ahi[base_d] = dh;  *(ushort4*)&Alo[base_d] = dl;
    }
    for (int rep = 0; rep < 2; ++rep) {            // x: 32 m x 16 float4
        int flat = rep * 256 + tid;
        int m = flat >> 4, f4 = flat & 15;
        int mg = m0 + m;
        int b = mg >> lg, ii = Lt + (mg & msk);
        int g = b * NPT + ii;
        float4 x4 = Ff4[(size_t)g * 16 + f4];
        float xv[4] = {x4.x, x4.y, x4.z, x4.w};
        int rt = m >> 4, lm = m & 15;
        int ks = 8 + (f4 >> 3);
        int lane_ = lm + 16 * ((f4 >> 1) & 3);
        int j0 = (f4 & 1) * 4;
        ushort4 xh, xl;
        u16* xhp = (u16*)&xh; u16* xlp = (u16*)&xl;
#pragma unroll
        for (int e = 0; e < 4; ++e) {
            u16 a = bf_hi(xv[e]); xhp[e] = a; xlp[e] = bf_hi(xv[e] - bf_f(a));
        }
        int base = ((rt * 18 + ks) * 64 + lane_) * 8 + j0;
        *(ushort4*)&Ahi[base] = xh;  *(ushort4*)&Alo[base] = xl;
    }
    __syncthreads();

    f32x4 acc[2][NCT];
#pragma unroll
    for (int rt = 0; rt < 2; ++rt)
#pragma unroll
        for (int i = 0; i < NCT; ++i) acc[rt][i] = (f32x4){0.f, 0.f, 0.f, 0.f};

    for (int G = 0; G < 10; ++G) {
        bf16x8 ah[2], al[2];
#pragma unroll
        for (int rt = 0; rt < 2; ++rt) {
            ah[rt] = *(const bf16x8*)&Ahi[((rt * 18 + G) * 64 + lane) * 8];
            al[rt] = *(const bf16x8*)&Alo[((rt * 18 + G) * 64 + lane) * 8];
        }
#pragma unroll
        for (int ctl = 0; ctl < NCT; ++ctl) {
            if (ctl % 5 == 4) continue;
            size_t slot = (size_t)((ctbase + ctl) * 10 + G) * 512 + lane * 8;
            bf16x8 bh = *(const bf16x8*)(Bhi + slot);
            bf16x8 bl = *(const bf16x8*)(Blo + slot);
#pragma unroll
            for (int rt = 0; rt < 2; ++rt) {
                acc[rt][ctl] = __builtin_amdgcn_mfma_f32_16x16x32_bf16(ah[rt], bh, acc[rt][ctl], 0, 0, 0);
                acc[rt][ctl] = __builtin_amdgcn_mfma_f32_16x16x32_bf16(ah[rt], bl, acc[rt][ctl], 0, 0, 0);
                acc[rt][ctl] = __builtin_amdgcn_mfma_f32_16x16x32_bf16(al[rt], bh, acc[rt][ctl], 0, 0, 0);
            }
        }
    }
    for (int G = 10; G < 18; ++G) {
        bf16x8 ah[2], al[2];
#pragma unroll
        for (int rt = 0; rt < 2; ++rt) {
            ah[rt] = *(const bf16x8*)&Ahi[((rt * 18 + G) * 64 + lane) * 8];
            al[rt] = *(const bf16x8*)&Alo[((rt * 18 + G) * 64 + lane) * 8];
        }
#pragma unroll
        for (int ctl = 4; ctl < NCT; ctl += 5) {
            size_t slot = (size_t)((ctbase + ctl) * 10 + (G - 10)) * 512 + lane * 8;
            bf16x8 bh = *(const bf16x8*)(Bhi + slot);
            bf16x8 bl = *(const bf16x8*)(Blo + slot);
#pragma unroll
            for (int rt = 0; rt < 2; ++rt) {
                acc[rt][ctl] = __builtin_amdgcn_mfma_f32_16x16x32_bf16(ah[rt], bh, acc[rt][ctl], 0, 0, 0);
                acc[rt][ctl] = __builtin_amdgcn_mfma_f32_16x16x32_bf16(ah[rt], bl, acc[rt][ctl], 0, 0, 0);
                acc[rt][ctl] = __builtin_amdgcn_mfma_f32_16x16x32_bf16(al[rt], bh, acc[rt][ctl], 0, 0, 0);
            }
        }
    }
    __syncthreads();

    float* sc = (float*)smem + w * 2592;       // [32 rows][81] per wave (aliased over A)
    const int n = lane & 15, q = lane >> 4;
#pragma unroll
    for (int sub = 0; sub < SUBS; ++sub) {
#pragma unroll
        for (int rt = 0; rt < 2; ++rt)
#pragma unroll
            for (int s = 0; s < 5; ++s) {
                f32x4 v = acc[rt][sub * 5 + s];
#pragma unroll
                for (int r = 0; r < 4; ++r)
                    sc[(rt * 16 + q * 4 + r) * 81 + s * 16 + n] = v[r];
            }
        int hb_abs = ctbase / 5 + sub;
        int jHb = hb_abs * 16;
        for (int it = 0; it < 8; ++it) {
            int idx = it * 64 + lane;
            int m = idx >> 4, jl = idx & 15;
            int jH = jHb + jl;
            float Ci  = sc[m * 81 + jl];
            float Co  = sc[m * 81 + 16 + jl];
            float Cu  = sc[m * 81 + 32 + jl];
            float Cfs = sc[m * 81 + 48 + jl];
            float Cfd = sc[m * 81 + 64 + jl];
            int mg = m0 + m;
            int b = mg >> lg, ii = Lt + (mg & msk);
            size_t g = (size_t)b * NPT + ii;
            float iv = sigf(Ci + biou[jH]);
            float ov = sigf(Co + biou[256 + jH]);
            float uv = tanh_fast(Cu + biou[512 + jH]);
            size_t gc = g + ii + 1;
            float bF = bfv[jH];
            float f1 = sigf(0.5f * (Cfs + Cfd) + bF);
            float f2 = sigf(0.5f * (Cfs - Cfd) + bF);
            float cv = iv * uv + f1 * c[gc * HH + jH] + f2 * c[(gc + 1) * HH + jH];
            float hv = ov * tanh_fast(cv);
            c[g * HH + jH] = cv;
            h[g * HH + jH] = hv;
        }
    }
}

// ---------------------------------------------------------------------------
// Head, 2-phase. Phase 1: 1024 blocks (8/tree) partial row-sums (full chip).
// Phase 2: 128 blocks combine + lin0 + ReLU + lin1.
// ---------------------------------------------------------------------------
__global__ __launch_bounds__(256) void head_partial(
    const float* __restrict__ h, float* __restrict__ hp)
{
    int blk = blockIdx.x;
    int b = blk >> 3, p = blk & 7, tid = threadIdx.x;
    const float* hb = h + ((size_t)b * NPT + p * 32) * HH;
    int rows = (p == 7) ? 31 : 32;
    float a0 = 0.f, a1 = 0.f, a2 = 0.f, a3 = 0.f;
    int i = 0;
    for (; i + 3 < rows; i += 4) {
        a0 += hb[(size_t)(i + 0) * HH + tid];
        a1 += hb[(size_t)(i + 1) * HH + tid];
        a2 += hb[(size_t)(i + 2) * HH + tid];
        a3 += hb[(size_t)(i + 3) * HH + tid];
    }
    for (; i < rows; ++i) a0 += hb[(size_t)i * HH + tid];
    hp[(size_t)blk * HH + tid] = a0 + a1 + a2 + a3;
}

__global__ __launch_bounds__(256) void head_final(
    const float* __restrict__ hp,
    const float* __restrict__ l0w, const float* __restrict__ l0b,
    const float* __restrict__ l1w, const float* __restrict__ l1b,
    float* __restrict__ out)
{
    __shared__ float ms[HH];
    __shared__ float red[4];
    int b = blockIdx.x, tid = threadIdx.x;
    float a = 0.f;
#pragma unroll
    for (int p = 0; p < 8; ++p) a += hp[(size_t)(b * 8 + p) * HH + tid];
    ms[tid] = a * (1.0f / (float)NPT);
    __syncthreads();

    const float4* L0 = (const float4*)(l0w + (size_t)tid * HH);
    float y = 0.f;
    for (int k4 = 0; k4 < 64; ++k4) {
        float4 wv = L0[k4];
        float4 m4 = ((const float4*)ms)[k4];
        y += wv.x * m4.x + wv.y * m4.y + wv.z * m4.z + wv.w * m4.w;
    }
    y += l0b[tid];
    y = fmaxf(y, 0.f);
    float v = y * l1w[tid];
    for (int off = 32; off > 0; off >>= 1) v += __shfl_down(v, off, 64);
    if ((tid & 63) == 0) red[tid >> 6] = v;
    __syncthreads();
    if (tid == 0) out[b] = red[0] + red[1] + red[2] + red[3] + l1b[0];
}

// ---------------------------------------------------------------------------
extern "C" void kernel_launch(void* const* d_in, const int* in_sizes, int n_in,
                              void* d_out, int out_size, void* d_ws, size_t ws_size,
                              hipStream_t stream)
{
    const float* feat = (const float*)d_in[0];
    const float* Wiou = (const float*)d_in[4];
    const float* biou = (const float*)d_in[5];
    const float* Uiou = (const float*)d_in[6];
    const float* Wf   = (const float*)d_in[7];
    const float* bfv  = (const float*)d_in[8];
    const float* Uf   = (const float*)d_in[9];
    const float* l0w  = (const float*)d_in[10];
    const float* l0b  = (const float*)d_in[11];
    const float* l1w  = (const float*)d_in[12];
    const float* l1b  = (const float*)d_in[13];

    float* h  = (float*)d_ws;
    float* c  = h + (size_t)NTOT * HH;
    u16* Bhi  = (u16*)(c + (size_t)NTOT * HH);
    u16* Blo  = Bhi + 409600;
    float* WxT = (float*)(Blo + 409600);
    float* hp  = WxT + 65536;

    // pack B (split bf16) + WxT (fp32, leaf): 409600 + 65536 elems
    pack_B<<<1856, 256, 0, stream>>>(Uiou, Uf, Wiou, Wf, Bhi, Blo, WxT);

    // leaves: fp32, 16/block
    leaf_v2<<<1024, 256, 0, stream>>>(feat, WxT, biou, h, c);
    // t=1: M=8192, NCT=10 (CSPLIT=2) -> 512 blocks
    level_mfma<10><<<512, 256, 0, stream>>>(feat, Bhi, Blo, biou, bfv, h, c, 63, 6);
    // t=2..7: NCT=5 (CSPLIT=4)
    level_mfma<5><<<512, 256, 0, stream>>>(feat, Bhi, Blo, biou, bfv, h, c, 31, 5);
    level_mfma<5><<<256, 256, 0, stream>>>(feat, Bhi, Blo, biou, bfv, h, c, 15, 4);
    level_mfma<5><<<128, 256, 0, stream>>>(feat, Bhi, Blo, biou, bfv, h, c, 7, 3);
    level_mfma<5><<<64, 256, 0, stream>>>(feat, Bhi, Blo, biou, bfv, h, c, 3, 2);
    level_mfma<5><<<32, 256, 0, stream>>>(feat, Bhi, Blo, biou, bfv, h, c, 1, 1);
    level_mfma<5><<<16, 256, 0, stream>>>(feat, Bhi, Blo, biou, bfv, h, c, 0, 0);

    head_partial<<<1024, 256, 0, stream>>>(h, hp);
    head_final<<<B_TREES, 256, 0, stream>>>(hp, l0w, l0b, l1w, l1b, (float*)d_out);
}

// Round 9
// 297.078 us; speedup vs baseline: 1.1451x; 1.0017x over previous
//
#include <hip/hip_runtime.h>

#define B_TREES 128
#define NPT 255
#define NTOT (B_TREES * NPT)   // 32640
#define FIN 64
#define HH 256

typedef short bf16x8 __attribute__((ext_vector_type(8)));
typedef float f32x4  __attribute__((ext_vector_type(4)));
typedef unsigned short u16;

__device__ __forceinline__ float sigf(float x) {
    return __frcp_rn(1.0f + __expf(-x));
}
__device__ __forceinline__ float tanh_fast(float x) {
    return __builtin_fmaf(2.0f, sigf(2.0f * x), -1.0f);
}
__device__ __forceinline__ u16 bf_hi(float v) {       // round-to-nearest-even bf16
    unsigned u = __float_as_uint(v);
    return (u16)((u + 0x7FFFu + ((u >> 16) & 1u)) >> 16);
}
__device__ __forceinline__ float bf_f(u16 b) { return __uint_as_float(((unsigned)b) << 16); }

// ---------------------------------------------------------------------------
// pack_B: B[576 x 1280] in MFMA-B-frag layout, split bf16 hi+lo, PLUS fp32
// WxT for the fp32 leaf kernel.
// ---------------------------------------------------------------------------
__global__ __launch_bounds__(256) void pack_B(
    const float* __restrict__ Uiou, const float* __restrict__ Uf,
    const float* __restrict__ Wiou, const float* __restrict__ Wf,
    u16* __restrict__ Bhi, u16* __restrict__ Blo, float* __restrict__ WxT)
{
    int idx = blockIdx.x * 256 + threadIdx.x;   // grid covers 409600 + 65536
    if (idx < 409600) {
        int j    = idx & 7;
        int lane = (idx >> 3) & 63;
        int ksl  = (idx >> 9) % 10;
        int ct   = idx / 5120;
        int s = ct % 5, hb = ct / 5;
        int n = lane & 15, q = lane >> 4;
        int jH = hb * 16 + n;
        int k = (s < 4 ? ksl * 32 : 320 + ksl * 32) + q * 8 + j;
        float v = 0.0f;
        if (s == 4) {
            if (k < 576) v = Uf[(size_t)jH * HH + (k - 320)];
        } else {
            if (k < 256) {
                v = (s < 3) ? Uiou[(size_t)(s * 256 + jH) * HH + k]
                            : Uf[(size_t)jH * HH + k];
            } else {
                int kw = k - 256;
                v = (s < 3) ? Wiou[(size_t)(s * 256 + jH) * FIN + kw]
                            : 2.0f * Wf[(size_t)jH * FIN + kw];
            }
        }
        u16 hi = bf_hi(v);
        u16 lo = bf_hi(v - bf_f(hi));
        Bhi[idx] = hi;
        Blo[idx] = lo;
    } else {
        int idx2 = idx - 409600;   // < 65536
        int k = idx2 >> 10, j = idx2 & 1023;
        float v = (j < 768) ? Wiou[(size_t)j * 64 + k] : 2.0f * Wf[(size_t)(j - 768) * 64 + k];
        WxT[(size_t)(k >> 2) * 4096 + j * 4 + (k & 3)] = v;
    }
}

// ---------------------------------------------------------------------------
// Leaves, fp32. R8: NB=16 @1024 blocks was latency-bound (VALUBusy 60%,
// 48 accs/thread blocked load pipelining). R9: NB=8, 2048 blocks — half the
// accumulators, double the resident waves. Aggregate weight traffic 402 MB
// (~12 us L2) still cheap.
// ---------------------------------------------------------------------------
__global__ __launch_bounds__(256) void leaf_v2(
    const float* __restrict__ feat,
    const float* __restrict__ WxT, const float* __restrict__ biou,
    float* __restrict__ h, float* __restrict__ c)
{
    const int NB = 8;
    __shared__ float xs[NB][FIN];
    int tid = threadIdx.x;
    int l0 = blockIdx.x * NB;
    int b = l0 >> 7;
    int g0 = b * NPT + 127 + (l0 & 127);
    const float* fb = feat + (size_t)g0 * FIN;
    for (int i = tid; i < NB * FIN; i += 256) ((float*)xs)[i] = fb[i];
    __syncthreads();

    float ai[NB], ao[NB], au[NB];
#pragma unroll
    for (int n = 0; n < NB; ++n) { ai[n] = 0.f; ao[n] = 0.f; au[n] = 0.f; }

    const float4* WxT4 = (const float4*)WxT;
    for (int k4 = 0; k4 < 16; ++k4) {
        size_t base = (size_t)k4 * 1024 + tid;
        float4 wi = WxT4[base], wo = WxT4[base + 256], wu = WxT4[base + 512];
#pragma unroll
        for (int n = 0; n < NB; ++n) {
            float4 x4 = ((const float4*)xs[n])[k4];
            ai[n] += wi.x * x4.x + wi.y * x4.y + wi.z * x4.z + wi.w * x4.w;
            ao[n] += wo.x * x4.x + wo.y * x4.y + wo.z * x4.z + wo.w * x4.w;
            au[n] += wu.x * x4.x + wu.y * x4.y + wu.z * x4.z + wu.w * x4.w;
        }
    }

    float bi = biou[tid], bo = biou[tid + 256], bu = biou[tid + 512];
#pragma unroll
    for (int n = 0; n < NB; ++n) {
        float iv = sigf(ai[n] + bi);
        float ov = sigf(ao[n] + bo);
        float uv = tanh_fast(au[n] + bu);
        float cv = iv * uv;
        float hv = ov * tanh_fast(cv);
        c[(size_t)(g0 + n) * HH + tid] = cv;
        h[(size_t)(g0 + n) * HH + tid] = hv;
    }
}

// ---------------------------------------------------------------------------
// level_mfma: 256 thr = 4 waves, 32 nodes/block, split-bf16.
// R9: ALL levels use NCT=5 (CSPLIT=4). At NCT=10 a wave needed 20 B-loads
// (80 VGPRs) in flight per G-step — at VGPR=88 the compiler couldn't
// pipeline, measured 48 us on t=1. NCT=5 needs 10 (~40 regs).
// R7 lesson: never collapse the col-split (per-CU B-wall).
// ---------------------------------------------------------------------------
template<int NCT>
__global__ __launch_bounds__(256, 2) void level_mfma(
    const float* __restrict__ feat,
    const u16* __restrict__ Bhi, const u16* __restrict__ Blo,
    const float* __restrict__ biou, const float* __restrict__ bfv,
    float* __restrict__ h, float* __restrict__ c,
    int Lt, int lg)
{
    constexpr int CSPLIT = 20 / NCT;
    constexpr int SUBS = NCT / 5;
    __shared__ char smem[73728];
    short* Ahi = (short*)smem;
    short* Alo = (short*)(smem + 36864);

    const int tid = threadIdx.x;
    const int lane = tid & 63, w = tid >> 6;
    const int cs = blockIdx.x % CSPLIT;
    const int rb = blockIdx.x / CSPLIT;
    const int m0 = rb * 32;
    const int msk = (1 << lg) - 1;
    const int ctbase = cs * 4 * NCT + w * NCT;

    const float4* Hf4 = (const float4*)h;
    const float4* Ff4 = (const float4*)feat;

    for (int rep = 0; rep < 8; ++rep) {            // hs/hd: 32 m x 64 float4
        int flat = rep * 256 + tid;
        int m = flat >> 6, f4 = flat & 63;
        int mg = m0 + m;
        int b = mg >> lg, ii = Lt + (mg & msk);
        int gc = b * NPT + 2 * ii + 1;
        float4 h1 = Hf4[(size_t)gc * 64 + f4];
        float4 h2 = Hf4[(size_t)(gc + 1) * 64 + f4];
        float hsv[4] = {h1.x + h2.x, h1.y + h2.y, h1.z + h2.z, h1.w + h2.w};
        float hdv[4] = {h1.x - h2.x, h1.y - h2.y, h1.z - h2.z, h1.w - h2.w};
        int rt = m >> 4, lm = m & 15;
        int ks = f4 >> 3;
        int lane_ = lm + 16 * ((f4 >> 1) & 3);
        int j0 = (f4 & 1) * 4;
        ushort4 sh, sl, dh, dl;
        u16* shp = (u16*)&sh; u16* slp = (u16*)&sl;
        u16* dhp = (u16*)&dh; u16* dlp = (u16*)&dl;
#pragma unroll
        for (int e = 0; e < 4; ++e) {
            u16 a = bf_hi(hsv[e]); shp[e] = a; slp[e] = bf_hi(hsv[e] - bf_f(a));
            u16 d = bf_hi(hdv[e]); dhp[e] = d; dlp[e] = bf_hi(hdv[e] - bf_f(d));
        }
        int base_s = ((rt * 18 + ks) * 64 + lane_) * 8 + j0;
        int base_d = ((rt * 18 + ks + 10) * 64 + lane_) * 8 + j0;
        *(ushort4*)&Ahi[base_s] = sh;  *(ushort4*)&Alo[base_s] = sl;
        *(ushort4*)&Ahi[base_d] = dh;  *(ushort4*)&Alo[base_d] = dl;
    }
    for (int rep = 0; rep < 2; ++rep) {            // x: 32 m x 16 float4
        int flat = rep * 256 + tid;
        int m = flat >> 4, f4 = flat & 15;
        int mg = m0 + m;
        int b = mg >> lg, ii = Lt + (mg & msk);
        int g = b * NPT + ii;
        float4 x4 = Ff4[(size_t)g * 16 + f4];
        float xv[4] = {x4.x, x4.y, x4.z, x4.w};
        int rt = m >> 4, lm = m & 15;
        int ks = 8 + (f4 >> 3);
        int lane_ = lm + 16 * ((f4 >> 1) & 3);
        int j0 = (f4 & 1) * 4;
        ushort4 xh, xl;
        u16* xhp = (u16*)&xh; u16* xlp = (u16*)&xl;
#pragma unroll
        for (int e = 0; e < 4; ++e) {
            u16 a = bf_hi(xv[e]); xhp[e] = a; xlp[e] = bf_hi(xv[e] - bf_f(a));
        }
        int base = ((rt * 18 + ks) * 64 + lane_) * 8 + j0;
        *(ushort4*)&Ahi[base] = xh;  *(ushort4*)&Alo[base] = xl;
    }
    __syncthreads();

    f32x4 acc[2][NCT];
#pragma unroll
    for (int rt = 0; rt < 2; ++rt)
#pragma unroll
        for (int i = 0; i < NCT; ++i) acc[rt][i] = (f32x4){0.f, 0.f, 0.f, 0.f};

    for (int G = 0; G < 10; ++G) {
        bf16x8 ah[2], al[2];
#pragma unroll
        for (int rt = 0; rt < 2; ++rt) {
            ah[rt] = *(const bf16x8*)&Ahi[((rt * 18 + G) * 64 + lane) * 8];
            al[rt] = *(const bf16x8*)&Alo[((rt * 18 + G) * 64 + lane) * 8];
        }
#pragma unroll
        for (int ctl = 0; ctl < NCT; ++ctl) {
            if (ctl % 5 == 4) continue;
            size_t slot = (size_t)((ctbase + ctl) * 10 + G) * 512 + lane * 8;
            bf16x8 bh = *(const bf16x8*)(Bhi + slot);
            bf16x8 bl = *(const bf16x8*)(Blo + slot);
#pragma unroll
            for (int rt = 0; rt < 2; ++rt) {
                acc[rt][ctl] = __builtin_amdgcn_mfma_f32_16x16x32_bf16(ah[rt], bh, acc[rt][ctl], 0, 0, 0);
                acc[rt][ctl] = __builtin_amdgcn_mfma_f32_16x16x32_bf16(ah[rt], bl, acc[rt][ctl], 0, 0, 0);
                acc[rt][ctl] = __builtin_amdgcn_mfma_f32_16x16x32_bf16(al[rt], bh, acc[rt][ctl], 0, 0, 0);
            }
        }
    }
    for (int G = 10; G < 18; ++G) {
        bf16x8 ah[2], al[2];
#pragma unroll
        for (int rt = 0; rt < 2; ++rt) {
            ah[rt] = *(const bf16x8*)&Ahi[((rt * 18 + G) * 64 + lane) * 8];
            al[rt] = *(const bf16x8*)&Alo[((rt * 18 + G) * 64 + lane) * 8];
        }
#pragma unroll
        for (int ctl = 4; ctl < NCT; ctl += 5) {
            size_t slot = (size_t)((ctbase + ctl) * 10 + (G - 10)) * 512 + lane * 8;
            bf16x8 bh = *(const bf16x8*)(Bhi + slot);
            bf16x8 bl = *(const bf16x8*)(Blo + slot);
#pragma unroll
            for (int rt = 0; rt < 2; ++rt) {
                acc[rt][ctl] = __builtin_amdgcn_mfma_f32_16x16x32_bf16(ah[rt], bh, acc[rt][ctl], 0, 0, 0);
                acc[rt][ctl] = __builtin_amdgcn_mfma_f32_16x16x32_bf16(ah[rt], bl, acc[rt][ctl], 0, 0, 0);
                acc[rt][ctl] = __builtin_amdgcn_mfma_f32_16x16x32_bf16(al[rt], bh, acc[rt][ctl], 0, 0, 0);
            }
        }
    }
    __syncthreads();

    float* sc = (float*)smem + w * 2592;       // [32 rows][81] per wave (aliased over A)
    const int n = lane & 15, q = lane >> 4;
#pragma unroll
    for (int sub = 0; sub < SUBS; ++sub) {
#pragma unroll
        for (int rt = 0; rt < 2; ++rt)
#pragma unroll
            for (int s = 0; s < 5; ++s) {
                f32x4 v = acc[rt][sub * 5 + s];
#pragma unroll
                for (int r = 0; r < 4; ++r)
                    sc[(rt * 16 + q * 4 + r) * 81 + s * 16 + n] = v[r];
            }
        int hb_abs = ctbase / 5 + sub;
        int jHb = hb_abs * 16;
        for (int it = 0; it < 8; ++it) {
            int idx = it * 64 + lane;
            int m = idx >> 4, jl = idx & 15;
            int jH = jHb + jl;
            float Ci  = sc[m * 81 + jl];
            float Co  = sc[m * 81 + 16 + jl];
            float Cu  = sc[m * 81 + 32 + jl];
            float Cfs = sc[m * 81 + 48 + jl];
            float Cfd = sc[m * 81 + 64 + jl];
            int mg = m0 + m;
            int b = mg >> lg, ii = Lt + (mg & msk);
            size_t g = (size_t)b * NPT + ii;
            float iv = sigf(Ci + biou[jH]);
            float ov = sigf(Co + biou[256 + jH]);
            float uv = tanh_fast(Cu + biou[512 + jH]);
            size_t gc = g + ii + 1;
            float bF = bfv[jH];
            float f1 = sigf(0.5f * (Cfs + Cfd) + bF);
            float f2 = sigf(0.5f * (Cfs - Cfd) + bF);
            float cv = iv * uv + f1 * c[gc * HH + jH] + f2 * c[(gc + 1) * HH + jH];
            float hv = ov * tanh_fast(cv);
            c[g * HH + jH] = cv;
            h[g * HH + jH] = hv;
        }
    }
}

// ---------------------------------------------------------------------------
// Head, 2-phase. Phase 1: 1024 blocks (8/tree) partial row-sums (full chip).
// Phase 2: 128 blocks combine + lin0 + ReLU + lin1.
// ---------------------------------------------------------------------------
__global__ __launch_bounds__(256) void head_partial(
    const float* __restrict__ h, float* __restrict__ hp)
{
    int blk = blockIdx.x;
    int b = blk >> 3, p = blk & 7, tid = threadIdx.x;
    const float* hb = h + ((size_t)b * NPT + p * 32) * HH;
    int rows = (p == 7) ? 31 : 32;
    float a0 = 0.f, a1 = 0.f, a2 = 0.f, a3 = 0.f;
    int i = 0;
    for (; i + 3 < rows; i += 4) {
        a0 += hb[(size_t)(i + 0) * HH + tid];
        a1 += hb[(size_t)(i + 1) * HH + tid];
        a2 += hb[(size_t)(i + 2) * HH + tid];
        a3 += hb[(size_t)(i + 3) * HH + tid];
    }
    for (; i < rows; ++i) a0 += hb[(size_t)i * HH + tid];
    hp[(size_t)blk * HH + tid] = a0 + a1 + a2 + a3;
}

__global__ __launch_bounds__(256) void head_final(
    const float* __restrict__ hp,
    const float* __restrict__ l0w, const float* __restrict__ l0b,
    const float* __restrict__ l1w, const float* __restrict__ l1b,
    float* __restrict__ out)
{
    __shared__ float ms[HH];
    __shared__ float red[4];
    int b = blockIdx.x, tid = threadIdx.x;
    float a = 0.f;
#pragma unroll
    for (int p = 0; p < 8; ++p) a += hp[(size_t)(b * 8 + p) * HH + tid];
    ms[tid] = a * (1.0f / (float)NPT);
    __syncthreads();

    const float4* L0 = (const float4*)(l0w + (size_t)tid * HH);
    float y = 0.f;
    for (int k4 = 0; k4 < 64; ++k4) {
        float4 wv = L0[k4];
        float4 m4 = ((const float4*)ms)[k4];
        y += wv.x * m4.x + wv.y * m4.y + wv.z * m4.z + wv.w * m4.w;
    }
    y += l0b[tid];
    y = fmaxf(y, 0.f);
    float v = y * l1w[tid];
    for (int off = 32; off > 0; off >>= 1) v += __shfl_down(v, off, 64);
    if ((tid & 63) == 0) red[tid >> 6] = v;
    __syncthreads();
    if (tid == 0) out[b] = red[0] + red[1] + red[2] + red[3] + l1b[0];
}

// ---------------------------------------------------------------------------
extern "C" void kernel_launch(void* const* d_in, const int* in_sizes, int n_in,
                              void* d_out, int out_size, void* d_ws, size_t ws_size,
                              hipStream_t stream)
{
    const float* feat = (const float*)d_in[0];
    const float* Wiou = (const float*)d_in[4];
    const float* biou = (const float*)d_in[5];
    const float* Uiou = (const float*)d_in[6];
    const float* Wf   = (const float*)d_in[7];
    const float* bfv  = (const float*)d_in[8];
    const float* Uf   = (const float*)d_in[9];
    const float* l0w  = (const float*)d_in[10];
    const float* l0b  = (const float*)d_in[11];
    const float* l1w  = (const float*)d_in[12];
    const float* l1b  = (const float*)d_in[13];

    float* h  = (float*)d_ws;
    float* c  = h + (size_t)NTOT * HH;
    u16* Bhi  = (u16*)(c + (size_t)NTOT * HH);
    u16* Blo  = Bhi + 409600;
    float* WxT = (float*)(Blo + 409600);
    float* hp  = WxT + 65536;

    // pack B (split bf16) + WxT (fp32, leaf): 409600 + 65536 elems
    pack_B<<<1856, 256, 0, stream>>>(Uiou, Uf, Wiou, Wf, Bhi, Blo, WxT);

    // leaves: fp32, 8/block, 2048 blocks
    leaf_v2<<<2048, 256, 0, stream>>>(feat, WxT, biou, h, c);
    // t=1: M=8192, NCT=5 (CSPLIT=4) -> 1024 blocks
    level_mfma<5><<<1024, 256, 0, stream>>>(feat, Bhi, Blo, biou, bfv, h, c, 63, 6);
    // t=2..7: NCT=5 (CSPLIT=4)
    level_mfma<5><<<512, 256, 0, stream>>>(feat, Bhi, Blo, biou, bfv, h, c, 31, 5);
    level_mfma<5><<<256, 256, 0, stream>>>(feat, Bhi, Blo, biou, bfv, h, c, 15, 4);
    level_mfma<5><<<128, 256, 0, stream>>>(feat, Bhi, Blo, biou, bfv, h, c, 7, 3);
    level_mfma<5><<<64, 256, 0, stream>>>(feat, Bhi, Blo, biou, bfv, h, c, 3, 2);
    level_mfma<5><<<32, 256, 0, stream>>>(feat, Bhi, Blo, biou, bfv, h, c, 1, 1);
    level_mfma<5><<<16, 256, 0, stream>>>(feat, Bhi, Blo, biou, bfv, h, c, 0, 0);

    head_partial<<<1024, 256, 0, stream>>>(h, hp);
    head_final<<<B_TREES, 256, 0, stream>>>(hp, l0w, l0b, l1w, l1b, (float*)d_out);
}